// Round 6
// baseline (1656.792 us; speedup 1.0000x reference)
//
#include <hip/hip_runtime.h>
#include <hip/hip_bf16.h>

#define S 512
#define HWSZ (512 * 512)

// K1: qkv[b,o,h,w] = sum_c x[b,c,h,w] * qkv_w[o,c]
// One thread per pixel; x row in 64 VGPRs; weights via wave-uniform (scalar)
// loads. Outputs unrolled x4 -> 4 independent FMA chains (ILP).
__global__ __launch_bounds__(256) void k_qkv(const float* __restrict__ x,
                                             const float* __restrict__ w,
                                             float* __restrict__ qkv) {
    int t = blockIdx.x * 256 + threadIdx.x;   // 0 .. B*HW-1  (B*HW = 524288)
    int b = t >> 18;                          // HW = 2^18
    int sp = t & (HWSZ - 1);
    const float* xp = x + (size_t)b * 64 * HWSZ + sp;
    float xr[64];
#pragma unroll
    for (int c = 0; c < 64; ++c) xr[c] = xp[(size_t)c * HWSZ];
    float* qp = qkv + (size_t)b * 192 * HWSZ + sp;
    for (int o = 0; o < 192; o += 4) {
        const float* w0 = w + o * 64;         // block-uniform -> s_load
        float a0 = 0.f, a1 = 0.f, a2 = 0.f, a3 = 0.f;
#pragma unroll
        for (int c = 0; c < 64; ++c) {
            float xv = xr[c];
            a0 = fmaf(xv, w0[c], a0);
            a1 = fmaf(xv, w0[64 + c], a1);
            a2 = fmaf(xv, w0[128 + c], a2);
            a3 = fmaf(xv, w0[192 + c], a3);
        }
        qp[(size_t)(o + 0) * HWSZ] = a0;
        qp[(size_t)(o + 1) * HWSZ] = a1;
        qp[(size_t)(o + 2) * HWSZ] = a2;
        qp[(size_t)(o + 3) * HWSZ] = a3;
    }
}

// K2: one block per 8x8 window. Depthwise 3x3 (halo from global qkv) ->
// l2norm(q,k) -> channel-covariance attn (8 heads, 8x8) -> attn@V -> proj -> out.
// Row stride 68 floats = 272 B: 16B-aligned (ds_read_b128-able) and
// bank = (4*row + lane) % 32 -> conflict-free for every uniform-row access.
__global__ __launch_bounds__(256) void k_attn(const float* __restrict__ qkv,
                                              const float* __restrict__ dw_w,
                                              const float* __restrict__ proj_w,
                                              const float* __restrict__ temp,
                                              float* __restrict__ out) {
    __shared__ __align__(16) float qs[64][68];
    __shared__ __align__(16) float ks[64][68];
    __shared__ __align__(16) float vs[64][68];
    __shared__ __align__(16) float stage[4800];   // 48 ch x 10 x 10 halo chunk
    __shared__ __align__(16) float attn[512];     // [(h*8+r)*8 + d]

    // XCD-chunked swizzle: 8192 blocks, 8 XCDs -> XCD k owns a contiguous
    // range of 1024 window ids (16 window-rows) for L2 halo reuse.
    const int orig = blockIdx.x;
    const int n = (orig & 7) * 1024 + (orig >> 3);   // b*4096 + hb*64 + wb
    const int b = n >> 12;
    const int hb = (n >> 6) & 63;
    const int wb = n & 63;
    const int t = threadIdx.x;
    const int lane = t & 63;
    const int wid = t >> 6;

    const int gy0 = hb * 8 - 1;
    const int gx0 = wb * 8 - 1;

    // ---- depthwise conv in 4 chunks of 48 channels ----
    for (int chunk = 0; chunk < 4; ++chunk) {
        __syncthreads();   // protect stage from previous chunk's readers
        for (int i = t; i < 4800; i += 256) {
            int cl = i / 100;
            int rem = i - cl * 100;
            int yy = rem / 10, xx = rem - (rem / 10) * 10;
            int gy = gy0 + yy, gx = gx0 + xx;
            float v = 0.f;
            if ((unsigned)gy < 512u && (unsigned)gx < 512u) {
                int gch = chunk * 48 + cl;
                v = qkv[((size_t)b * 192 + gch) * HWSZ + (size_t)gy * 512 + gx];
            }
            stage[i] = v;
        }
        __syncthreads();
        const int px = lane;
        const int y = px >> 3, xcol = px & 7;
        for (int i = 0; i < 12; ++i) {
            int cl = wid + 4 * i;                 // 0..47, wave-uniform
            int gch = chunk * 48 + cl;
            const float* wp = dw_w + gch * 9;     // -> s_load
            const float* sp2 = &stage[cl * 100 + y * 10 + xcol];
            float acc = 0.f;
#pragma unroll
            for (int dy = 0; dy < 3; ++dy)
#pragma unroll
                for (int dx = 0; dx < 3; ++dx)
                    acc = fmaf(sp2[dy * 10 + dx], wp[dy * 3 + dx], acc);
            if (gch < 64) qs[gch][px] = acc;
            else if (gch < 128) ks[gch - 64][px] = acc;
            else vs[gch - 128][px] = acc;
        }
    }
    __syncthreads();

    // ---- l2 normalize each q,k channel over its 64 window pixels ----
    for (int ch = wid; ch < 64; ch += 4) {       // ch wave-uniform
        float qv = qs[ch][lane];
        float s = qv * qv;
#pragma unroll
        for (int off = 32; off > 0; off >>= 1) s += __shfl_xor(s, off, 64);
        qs[ch][lane] = qv * (1.f / fmaxf(sqrtf(s), 1e-12f));

        float kv = ks[ch][lane];
        float s2 = kv * kv;
#pragma unroll
        for (int off = 32; off > 0; off >>= 1) s2 += __shfl_xor(s2, off, 64);
        ks[ch][lane] = kv * (1.f / fmaxf(sqrtf(s2), 1e-12f));
    }
    __syncthreads();

    // ---- attn logits: 8 heads x 8x8, dot over 64 px (float4 LDS reads) ----
    for (int f = t; f < 512; f += 256) {
        int h = f >> 6, r = (f >> 3) & 7, d = f & 7;
        const float* qrow = qs[h * 8 + r];
        const float* krow = ks[h * 8 + d];
        float acc = 0.f;
#pragma unroll
        for (int p = 0; p < 16; ++p) {
            float4 qv = *(const float4*)&qrow[p * 4];
            float4 kv = *(const float4*)&krow[p * 4];
            acc = fmaf(qv.x, kv.x, acc);
            acc = fmaf(qv.y, kv.y, acc);
            acc = fmaf(qv.z, kv.z, acc);
            acc = fmaf(qv.w, kv.w, acc);
        }
        attn[f] = acc * temp[h];   // h wave-uniform per iteration -> broadcast
    }
    __syncthreads();

    // ---- softmax over last dim (rows of 8) ----
    if (t < 64) {
        float* row = &attn[t * 8];
        float m = row[0];
#pragma unroll
        for (int d = 1; d < 8; ++d) m = fmaxf(m, row[d]);
        float sum = 0.f;
        float e[8];
#pragma unroll
        for (int d = 0; d < 8; ++d) { e[d] = __expf(row[d] - m); sum += e[d]; }
        float inv = 1.f / sum;
#pragma unroll
        for (int d = 0; d < 8; ++d) row[d] = e[d] * inv;
    }
    __syncthreads();

    // ---- out = attn @ v, into qs (q dead). V column hoisted to registers;
    //      attn rows read as float4 (row for channel c is attn[c*8..c*8+7]).
    {
        const int px = lane;
        float vcol[64];
#pragma unroll
        for (int d = 0; d < 64; ++d) vcol[d] = vs[d][px];   // uniform row, free
#pragma unroll
        for (int h = 0; h < 8; ++h) {
#pragma unroll
            for (int rr = 0; rr < 2; ++rr) {
                int c = h * 8 + wid + 4 * rr;    // covers all 64 ch across waves
                float4 a0 = *(const float4*)&attn[c * 8];
                float4 a1 = *(const float4*)&attn[c * 8 + 4];
                float acc = 0.f;
                acc = fmaf(a0.x, vcol[h * 8 + 0], acc);
                acc = fmaf(a0.y, vcol[h * 8 + 1], acc);
                acc = fmaf(a0.z, vcol[h * 8 + 2], acc);
                acc = fmaf(a0.w, vcol[h * 8 + 3], acc);
                acc = fmaf(a1.x, vcol[h * 8 + 4], acc);
                acc = fmaf(a1.y, vcol[h * 8 + 5], acc);
                acc = fmaf(a1.z, vcol[h * 8 + 6], acc);
                acc = fmaf(a1.w, vcol[h * 8 + 7], acc);
                qs[c][px] = acc;                 // uniform row write, free
            }
        }
    }
    __syncthreads();

    // ---- proj (64x64, SGPR weights): hoist pixel column to regs once ----
    {
        const int px = lane;
        float col[64];
#pragma unroll
        for (int c2 = 0; c2 < 64; ++c2) col[c2] = qs[c2][px]; // uniform row, free
        const int y = px >> 3, xcol = px & 7;
        size_t obase = (size_t)b * 64 * HWSZ + (size_t)(hb * 8 + y) * 512 + (wb * 8 + xcol);
        for (int j = 0; j < 16; ++j) {
            int o = wid + 4 * j;                  // wave-uniform
            const float* pw = proj_w + o * 64;    // -> s_load
            float acc = 0.f;
#pragma unroll
            for (int c2 = 0; c2 < 64; ++c2) acc = fmaf(pw[c2], col[c2], acc);
            out[obase + (size_t)o * HWSZ] = acc;
        }
    }
}

extern "C" void kernel_launch(void* const* d_in, const int* in_sizes, int n_in,
                              void* d_out, int out_size, void* d_ws, size_t ws_size,
                              hipStream_t stream) {
    const float* x      = (const float*)d_in[0];
    const float* qkv_w  = (const float*)d_in[1];
    const float* dw_w   = (const float*)d_in[2];
    const float* proj_w = (const float*)d_in[3];
    const float* temp   = (const float*)d_in[4];
    float* out = (float*)d_out;
    float* qkv = (float*)d_ws;   // 2*192*512*512*4 = 402,653,184 bytes

    k_qkv<<<dim3(2048), dim3(256), 0, stream>>>(x, qkv_w, qkv);
    k_attn<<<dim3(8192), dim3(256), 0, stream>>>(qkv, dw_w, proj_w, temp, out);
}

// Round 9
// 1638.205 us; speedup vs baseline: 1.0113x; 1.0113x over previous
//
#include <hip/hip_runtime.h>
#include <hip/hip_bf16.h>

#define S 512
#define HWSZ (512 * 512)

// ---------------- K1: qkv1[b,o,h,w] = sum_c x[b,c,h,w] * qkv_w[o,c] ----------
// UNTOUCHED (no dedicated counters yet; keep attribution clean).
__global__ __launch_bounds__(256) void k_qkv(const float* __restrict__ x,
                                             const float* __restrict__ w,
                                             float* __restrict__ qkv) {
    int t = blockIdx.x * 256 + threadIdx.x;   // 0 .. B*HW-1  (B*HW = 524288)
    int b = t >> 18;                          // HW = 2^18
    int sp = t & (HWSZ - 1);
    const float* xp = x + (size_t)b * 64 * HWSZ + sp;
    float xr[64];
#pragma unroll
    for (int c = 0; c < 64; ++c) xr[c] = xp[(size_t)c * HWSZ];
    float* qp = qkv + (size_t)b * 192 * HWSZ + sp;
    for (int o = 0; o < 192; o += 4) {
        const float* w0 = w + o * 64;         // block-uniform -> s_load
        float a0 = 0.f, a1 = 0.f, a2 = 0.f, a3 = 0.f;
#pragma unroll
        for (int c = 0; c < 64; ++c) {
            float xv = xr[c];
            a0 = fmaf(xv, w0[c], a0);
            a1 = fmaf(xv, w0[64 + c], a1);
            a2 = fmaf(xv, w0[128 + c], a2);
            a3 = fmaf(xv, w0[192 + c], a3);
        }
        qp[(size_t)(o + 0) * HWSZ] = a0;
        qp[(size_t)(o + 1) * HWSZ] = a1;
        qp[(size_t)(o + 2) * HWSZ] = a2;
        qp[(size_t)(o + 3) * HWSZ] = a3;
    }
}

// ---------------- K2a: depthwise 3x3, plane-major in -> window-major out -----
// One thread per output element. No LDS, no barriers -> latency hidden by TLP.
// qkv2 layout: [b][win(4096)][ch(192)][px(64)]  (one window = contiguous 48 KB)
__global__ __launch_bounds__(256) void k_dwconv(const float* __restrict__ qkv1,
                                                const float* __restrict__ dw_w,
                                                float* __restrict__ qkv2) {
    // XCD-chunked bijective swizzle: 393216 blocks = 8 * 49152.
    const int orig = blockIdx.x;
    const int nb = (orig & 7) * 49152 + (orig >> 3);
    const int bw  = nb / 48;                  // b*4096 + win
    const int chq = nb - bw * 48;
    const int b   = bw >> 12;
    const int win = bw & 4095;
    const int wy = win >> 6, wx = win & 63;
    const int t = threadIdx.x;
    const int px = t & 63;
    const int ch = chq * 4 + (t >> 6);        // wave-uniform
    const int y = px >> 3, x = px & 7;
    const int gy0 = wy * 8 + y - 1;
    const int gx0 = wx * 8 + x - 1;
    const float* plane = qkv1 + ((size_t)b * 192 + ch) * HWSZ;
    const float* wp = dw_w + ch * 9;          // wave-uniform -> s_load
    float acc = 0.f;
#pragma unroll
    for (int ky = 0; ky < 3; ++ky) {
        int gy = gy0 + ky;
#pragma unroll
        for (int kx = 0; kx < 3; ++kx) {
            int gx = gx0 + kx;
            float v = 0.f;
            if ((unsigned)gy < 512u && (unsigned)gx < 512u)
                v = plane[gy * 512 + gx];
            acc = fmaf(v, wp[ky * 3 + kx], acc);
        }
    }
    qkv2[(size_t)bw * 12288 + ch * 64 + px] = acc;   // 256 B/wave contiguous
}

// ---------------- K2b: per-window attention from window-major qkv2 -----------
// Contiguous 48 KB stage -> l2norm -> logits -> softmax -> attn@V -> proj.
// LDS [ch][64]: every access row-uniform with consecutive lanes -> conflict-free.
// 51.2 KB LDS -> 3 blocks/CU (was 2). 5 barriers (was 11).
__global__ __launch_bounds__(256) void k_attn2(const float* __restrict__ qkv2,
                                               const float* __restrict__ proj_w,
                                               const float* __restrict__ temp,
                                               float* __restrict__ out) {
    __shared__ __align__(16) float s[12288];    // [192][64]: q 0-63, k 64-127, v 128-191
    __shared__ __align__(16) float attn[512];   // [(h*8+r)*8 + d]

    const int n = blockIdx.x;                   // b*4096 + win (no swizzle: zero reuse)
    const int b = n >> 12;
    const int hb = (n >> 6) & 63;
    const int wb = n & 63;
    const int t = threadIdx.x;
    const int lane = t & 63;
    const int wid = t >> 6;

    // ---- stage: one contiguous 49152 B block, fully coalesced ----
    {
        const float* src = qkv2 + (size_t)n * 12288;
#pragma unroll
        for (int j = 0; j < 12; ++j) {
            int idx = (j * 256 + t) * 4;
            *(float4*)&s[idx] = *(const float4*)&src[idx];
        }
    }
    __syncthreads();

    // ---- l2 normalize each q,k channel over its 64 window pixels ----
    for (int ch = wid; ch < 64; ch += 4) {       // ch wave-uniform
        float qv = s[ch * 64 + lane];
        float sq = qv * qv;
#pragma unroll
        for (int off = 32; off > 0; off >>= 1) sq += __shfl_xor(sq, off, 64);
        s[ch * 64 + lane] = qv * (1.f / fmaxf(sqrtf(sq), 1e-12f));

        float kv = s[(64 + ch) * 64 + lane];
        float sk = kv * kv;
#pragma unroll
        for (int off = 32; off > 0; off >>= 1) sk += __shfl_xor(sk, off, 64);
        s[(64 + ch) * 64 + lane] = kv * (1.f / fmaxf(sqrtf(sk), 1e-12f));
    }
    __syncthreads();

    // ---- attn logits: 8 heads x 8x8, dot over 64 px (b128 broadcast reads) ----
    for (int f = t; f < 512; f += 256) {
        int h = f >> 6, r = (f >> 3) & 7, d = f & 7;
        const float* qrow = &s[(h * 8 + r) * 64];
        const float* krow = &s[(64 + h * 8 + d) * 64];
        float acc = 0.f;
#pragma unroll
        for (int p = 0; p < 16; ++p) {
            float4 qv = *(const float4*)&qrow[p * 4];
            float4 kv = *(const float4*)&krow[p * 4];
            acc = fmaf(qv.x, kv.x, acc);
            acc = fmaf(qv.y, kv.y, acc);
            acc = fmaf(qv.z, kv.z, acc);
            acc = fmaf(qv.w, kv.w, acc);
        }
        attn[f] = acc * temp[h];   // h wave-uniform per iteration -> broadcast
    }
    __syncthreads();

    // ---- softmax over last dim (rows of 8) ----
    if (t < 64) {
        float* row = &attn[t * 8];
        float m = row[0];
#pragma unroll
        for (int d = 1; d < 8; ++d) m = fmaxf(m, row[d]);
        float sum = 0.f;
        float e[8];
#pragma unroll
        for (int d = 0; d < 8; ++d) { e[d] = __expf(row[d] - m); sum += e[d]; }
        float inv = 1.f / sum;
#pragma unroll
        for (int d = 0; d < 8; ++d) row[d] = e[d] * inv;
    }
    __syncthreads();

    // ---- out = attn @ v, written into q region (dead after logits) ----
    {
        float vcol[64];
#pragma unroll
        for (int d = 0; d < 64; ++d) vcol[d] = s[(128 + d) * 64 + lane];
#pragma unroll
        for (int h = 0; h < 8; ++h) {
#pragma unroll
            for (int rr = 0; rr < 2; ++rr) {
                int c = h * 8 + wid + 4 * rr;    // covers all 64 ch across waves
                float4 a0 = *(const float4*)&attn[c * 8];
                float4 a1 = *(const float4*)&attn[c * 8 + 4];
                float acc = 0.f;
                acc = fmaf(a0.x, vcol[h * 8 + 0], acc);
                acc = fmaf(a0.y, vcol[h * 8 + 1], acc);
                acc = fmaf(a0.z, vcol[h * 8 + 2], acc);
                acc = fmaf(a0.w, vcol[h * 8 + 3], acc);
                acc = fmaf(a1.x, vcol[h * 8 + 4], acc);
                acc = fmaf(a1.y, vcol[h * 8 + 5], acc);
                acc = fmaf(a1.z, vcol[h * 8 + 6], acc);
                acc = fmaf(a1.w, vcol[h * 8 + 7], acc);
                s[c * 64 + lane] = acc;          // c%4==wid -> race-free partition
            }
        }
    }
    __syncthreads();

    // ---- proj (64x64, SGPR weights): hoist pixel column to regs once ----
    {
        float col[64];
#pragma unroll
        for (int c2 = 0; c2 < 64; ++c2) col[c2] = s[c2 * 64 + lane];
        const int y = lane >> 3, xcol = lane & 7;
        size_t obase = (size_t)b * 64 * HWSZ + (size_t)(hb * 8 + y) * 512 + (wb * 8 + xcol);
        for (int j = 0; j < 16; ++j) {
            int o = wid + 4 * j;                  // wave-uniform
            const float* pw = proj_w + o * 64;    // -> s_load
            float acc = 0.f;
#pragma unroll
            for (int c2 = 0; c2 < 64; ++c2) acc = fmaf(pw[c2], col[c2], acc);
            out[obase + (size_t)o * HWSZ] = acc;
        }
    }
}

// ---------------- Fallback K2 (verified r6): used only if ws too small -------
__global__ __launch_bounds__(256) void k_attn(const float* __restrict__ qkv,
                                              const float* __restrict__ dw_w,
                                              const float* __restrict__ proj_w,
                                              const float* __restrict__ temp,
                                              float* __restrict__ out) {
    __shared__ __align__(16) float qs[64][68];
    __shared__ __align__(16) float ks[64][68];
    __shared__ __align__(16) float vs[64][68];
    __shared__ __align__(16) float stage[4800];
    __shared__ __align__(16) float attn[512];

    const int orig = blockIdx.x;
    const int n = (orig & 7) * 1024 + (orig >> 3);
    const int b = n >> 12;
    const int hb = (n >> 6) & 63;
    const int wb = n & 63;
    const int t = threadIdx.x;
    const int lane = t & 63;
    const int wid = t >> 6;
    const int gy0 = hb * 8 - 1;
    const int gx0 = wb * 8 - 1;

    for (int chunk = 0; chunk < 4; ++chunk) {
        __syncthreads();
        for (int i = t; i < 4800; i += 256) {
            int cl = i / 100;
            int rem = i - cl * 100;
            int yy = rem / 10, xx = rem - (rem / 10) * 10;
            int gy = gy0 + yy, gx = gx0 + xx;
            float v = 0.f;
            if ((unsigned)gy < 512u && (unsigned)gx < 512u) {
                int gch = chunk * 48 + cl;
                v = qkv[((size_t)b * 192 + gch) * HWSZ + (size_t)gy * 512 + gx];
            }
            stage[i] = v;
        }
        __syncthreads();
        const int px = lane;
        const int y = px >> 3, xcol = px & 7;
        for (int i = 0; i < 12; ++i) {
            int cl = wid + 4 * i;
            int gch = chunk * 48 + cl;
            const float* wp = dw_w + gch * 9;
            const float* sp2 = &stage[cl * 100 + y * 10 + xcol];
            float acc = 0.f;
#pragma unroll
            for (int dy = 0; dy < 3; ++dy)
#pragma unroll
                for (int dx = 0; dx < 3; ++dx)
                    acc = fmaf(sp2[dy * 10 + dx], wp[dy * 3 + dx], acc);
            if (gch < 64) qs[gch][px] = acc;
            else if (gch < 128) ks[gch - 64][px] = acc;
            else vs[gch - 128][px] = acc;
        }
    }
    __syncthreads();

    for (int ch = wid; ch < 64; ch += 4) {
        float qv = qs[ch][lane];
        float sq = qv * qv;
#pragma unroll
        for (int off = 32; off > 0; off >>= 1) sq += __shfl_xor(sq, off, 64);
        qs[ch][lane] = qv * (1.f / fmaxf(sqrtf(sq), 1e-12f));
        float kv = ks[ch][lane];
        float sk = kv * kv;
#pragma unroll
        for (int off = 32; off > 0; off >>= 1) sk += __shfl_xor(sk, off, 64);
        ks[ch][lane] = kv * (1.f / fmaxf(sqrtf(sk), 1e-12f));
    }
    __syncthreads();

    for (int f = t; f < 512; f += 256) {
        int h = f >> 6, r = (f >> 3) & 7, d = f & 7;
        const float* qrow = qs[h * 8 + r];
        const float* krow = ks[h * 8 + d];
        float acc = 0.f;
#pragma unroll
        for (int p = 0; p < 16; ++p) {
            float4 qv = *(const float4*)&qrow[p * 4];
            float4 kv = *(const float4*)&krow[p * 4];
            acc = fmaf(qv.x, kv.x, acc);
            acc = fmaf(qv.y, kv.y, acc);
            acc = fmaf(qv.z, kv.z, acc);
            acc = fmaf(qv.w, kv.w, acc);
        }
        attn[f] = acc * temp[h];
    }
    __syncthreads();

    if (t < 64) {
        float* row = &attn[t * 8];
        float m = row[0];
#pragma unroll
        for (int d = 1; d < 8; ++d) m = fmaxf(m, row[d]);
        float sum = 0.f;
        float e[8];
#pragma unroll
        for (int d = 0; d < 8; ++d) { e[d] = __expf(row[d] - m); sum += e[d]; }
        float inv = 1.f / sum;
#pragma unroll
        for (int d = 0; d < 8; ++d) row[d] = e[d] * inv;
    }
    __syncthreads();

    {
        const int px = lane;
        float vcol[64];
#pragma unroll
        for (int d = 0; d < 64; ++d) vcol[d] = vs[d][px];
#pragma unroll
        for (int h = 0; h < 8; ++h) {
#pragma unroll
            for (int rr = 0; rr < 2; ++rr) {
                int c = h * 8 + wid + 4 * rr;
                float4 a0 = *(const float4*)&attn[c * 8];
                float4 a1 = *(const float4*)&attn[c * 8 + 4];
                float acc = 0.f;
                acc = fmaf(a0.x, vcol[h * 8 + 0], acc);
                acc = fmaf(a0.y, vcol[h * 8 + 1], acc);
                acc = fmaf(a0.z, vcol[h * 8 + 2], acc);
                acc = fmaf(a0.w, vcol[h * 8 + 3], acc);
                acc = fmaf(a1.x, vcol[h * 8 + 4], acc);
                acc = fmaf(a1.y, vcol[h * 8 + 5], acc);
                acc = fmaf(a1.z, vcol[h * 8 + 6], acc);
                acc = fmaf(a1.w, vcol[h * 8 + 7], acc);
                qs[c][px] = acc;
            }
        }
    }
    __syncthreads();

    {
        const int px = lane;
        float col[64];
#pragma unroll
        for (int c2 = 0; c2 < 64; ++c2) col[c2] = qs[c2][px];
        const int y = px >> 3, xcol = px & 7;
        size_t obase = (size_t)b * 64 * HWSZ + (size_t)(hb * 8 + y) * 512 + (wb * 8 + xcol);
        for (int j = 0; j < 16; ++j) {
            int o = wid + 4 * j;
            const float* pw = proj_w + o * 64;
            float acc = 0.f;
#pragma unroll
            for (int c2 = 0; c2 < 64; ++c2) acc = fmaf(pw[c2], col[c2], acc);
            out[obase + (size_t)o * HWSZ] = acc;
        }
    }
}

extern "C" void kernel_launch(void* const* d_in, const int* in_sizes, int n_in,
                              void* d_out, int out_size, void* d_ws, size_t ws_size,
                              hipStream_t stream) {
    const float* x      = (const float*)d_in[0];
    const float* qkv_w  = (const float*)d_in[1];
    const float* dw_w   = (const float*)d_in[2];
    const float* proj_w = (const float*)d_in[3];
    const float* temp   = (const float*)d_in[4];
    float* out = (float*)d_out;

    if (ws_size >= 805306368ull) {
        // Split path: qkv1 (plane-major, 402 MB) + qkv2 (window-major, 402 MB)
        float* qkv1 = (float*)d_ws;
        float* qkv2 = qkv1 + 100663296;   // 402653184 bytes / 4
        k_qkv<<<dim3(2048), dim3(256), 0, stream>>>(x, qkv_w, qkv1);
        k_dwconv<<<dim3(393216), dim3(256), 0, stream>>>(qkv1, dw_w, qkv2);
        k_attn2<<<dim3(8192), dim3(256), 0, stream>>>(qkv2, proj_w, temp, out);
    } else {
        // Fallback: verified round-6 path (needs only 402 MB)
        float* qkv1 = (float*)d_ws;
        k_qkv<<<dim3(2048), dim3(256), 0, stream>>>(x, qkv_w, qkv1);
        k_attn<<<dim3(8192), dim3(256), 0, stream>>>(qkv1, dw_w, proj_w, temp, out);
    }
}